// Round 9
// baseline (51.600 us; speedup 1.0000x reference)
//
#include <hip/hip_runtime.h>
#include <stdint.h>
#include <math.h>

typedef unsigned long long u64;

#define NT     1024
#define KOUT   512
#define DIRECT 1024     // L <= DIRECT: load rows directly, no filter
#define NSH    8        // work-queue shards (one counter per 64-byte line)
#define GRID   512      // 2 blocks/CU on 256 CUs
#define FNB    4096     // fallback histogram bins
#define FCAP   2048     // fallback candidate buffer

// Monotone float->uint32 map (order-preserving), exactly invertible.
__device__ __forceinline__ uint32_t fmap(float f) {
    uint32_t u = __float_as_uint(f);
    return (u & 0x80000000u) ? ~u : (u | 0x80000000u);
}
__device__ __forceinline__ float funmap(uint32_t m) {
    uint32_t u = (m & 0x80000000u) ? (m & 0x7fffffffu) : ~m;
    return __uint_as_float(u);
}
__device__ __forceinline__ u64 pack(float x, float y) {
    return ((u64)fmap(x) << 32) | (u64)fmap(y);
}
__device__ __forceinline__ u64 shfl_xor_u64(u64 v, int j) {
    uint32_t lo = __shfl_xor((uint32_t)v, j, 64);
    uint32_t hi = __shfl_xor((uint32_t)(v >> 32), j, 64);
    return ((u64)hi << 32) | lo;
}

// Acklam inverse normal CDF (float); ~1e-3 accuracy, exactness guarded downstream.
__device__ __forceinline__ float norm_icdf(float p) {
    const float a1=-3.969683028665376e+01f,a2= 2.209460984245205e+02f,a3=-2.759285104469687e+02f,
                a4= 1.383577518672690e+02f,a5=-3.066479806614716e+01f,a6= 2.506628277459239e+00f;
    const float b1=-5.447609879822406e+01f,b2= 1.615858368580409e+02f,b3=-1.556989798598866e+02f,
                b4= 6.680131188771972e+01f,b5=-1.328068155288572e+01f;
    const float c1=-7.784894002430293e-03f,c2=-3.223964580411365e-01f,c3=-2.400758277161838e+00f,
                c4=-2.549732539343734e+00f,c5= 4.374664141464968e+00f,c6= 2.938163982698783e+00f;
    const float d1= 7.784695709041462e-03f,d2= 3.224671290700398e-01f,d3= 2.445134137142996e+00f,
                d4= 3.754408661907416e+00f;
    if (p < 0.02425f) {
        float q = sqrtf(-2.0f * logf(p));
        return (((((c1*q+c2)*q+c3)*q+c4)*q+c5)*q+c6) / ((((d1*q+d2)*q+d3)*q+d4)*q+1.0f);
    } else if (p <= 0.97575f) {
        float q = p - 0.5f, r = q*q;
        return (((((a1*r+a2)*r+a3)*r+a4)*r+a5)*r+a6)*q / (((((b1*r+b2)*r+b3)*r+b4)*r+b5)*r+1.0f);
    } else {
        float q = sqrtf(-2.0f * logf(1.0f - p));
        return -(((((c1*q+c2)*q+c3)*q+c4)*q+c5)*q+c6) / ((((d1*q+d2)*q+d3)*q+d4)*q+1.0f);
    }
}

__global__ __launch_bounds__(NT) void topk_kernel(
    const float* __restrict__ corners, const int* __restrict__ lengths,
    float* __restrict__ out, uint32_t* __restrict__ ctrs, int M, int B)
{
    const int tid = threadIdx.x;
    __shared__ u64 sbuf[NT];         // filter staging + bitonic exchange
    __shared__ uint32_t hist[FNB];   // fallback only
    __shared__ u64 fcand[FCAP];      // fallback only
    __shared__ uint32_t shcnt, shT, shwork;

    const int per = (B + NSH - 1) / NSH;
    const int myshard = (int)(blockIdx.x) & (NSH - 1);

    for (int ss = 0; ss < NSH; ++ss) {
        const int s = (myshard + ss) & (NSH - 1);
        const int lo = s * per;
        const int hi = (B < lo + per) ? B : (lo + per);
        if (lo >= hi) continue;
        for (;;) {
            __syncthreads();                       // protect shwork/sbuf reuse
            if (tid == 0) shwork = atomicAdd(&ctrs[s * 16], 1u);
            __syncthreads();
            const int b = lo + (int)shwork;
            if (b >= hi) break;

            // ---------------- process batch b (round-7 body) ----------------
            int L = lengths[b];
            if (L < 0) L = 0;
            if (L > M) L = M;
            const int Kb = (L < KOUT) ? L : KOUT;
            float2* outb = (float2*)(out + (size_t)b * (2 * KOUT));
            const float2* cp = (const float2*)corners + (size_t)b * M;

            if (L == 0) {
                if (tid < KOUT) outb[tid] = make_float2(0.0f, 0.0f);
                continue;
            }

            u64 key = ~0ull;
            bool fb = false;

            if (L <= DIRECT) {
                if (tid < L) { float2 c = cp[tid]; key = pack(c.x, c.y); }
            } else {
                if (tid == 0) shcnt = 0u;
                __syncthreads();
                const float tau = norm_icdf(768.0f / (float)L) + 0.01f;
                const int lane = tid & 63;
                const float4* cp4 = (const float4*)cp;
                const int nv = L >> 1;

                for (int i = tid; i < nv; i += NT) {
                    float4 v = cp4[i];
                    bool k0 = (v.x <= tau), k1 = (v.z <= tau);
                    u64 m0 = __ballot(k0), m1 = __ballot(k1);
                    if (m0 | m1) {
                        int c0 = __popcll(m0);
                        uint32_t base = 0;
                        if (lane == 0) base = atomicAdd(&shcnt, (uint32_t)(c0 + __popcll(m1)));
                        base = __shfl(base, 0, 64);
                        u64 lt = ((u64)1 << lane) - 1ull;
                        if (k0) {
                            uint32_t sl = base + (uint32_t)__popcll(m0 & lt);
                            if (sl < NT) sbuf[sl] = pack(v.x, v.y);
                        }
                        if (k1) {
                            uint32_t sl = base + (uint32_t)(c0 + __popcll(m1 & lt));
                            if (sl < NT) sbuf[sl] = pack(v.z, v.w);
                        }
                    }
                }
                if ((L & 1) && tid == 0) {
                    float2 c = cp[L - 1];
                    if (c.x <= tau) {
                        uint32_t sl = atomicAdd(&shcnt, 1u);
                        if (sl < NT) sbuf[sl] = pack(c.x, c.y);
                    }
                }
                __syncthreads();
                const uint32_t n = shcnt;
                if (n < (uint32_t)Kb || n > NT) fb = true;   // block-uniform
                else if (tid < (int)n) key = sbuf[tid];
            }

            if (!fb) {
                __syncthreads();
                // ---- bitonic sort of 1024 keys, one per thread, ascending ----
                for (uint32_t k = 2; k <= NT; k <<= 1) {
                    uint32_t j = k >> 1;
                    for (; j >= 64; j >>= 1) {          // cross-wave: LDS
                        sbuf[tid] = key;
                        __syncthreads();
                        u64 pk = sbuf[tid ^ j];
                        __syncthreads();
                        bool lower = ((tid & j) == 0);
                        bool wantmin = (((tid & k) == 0) == lower);
                        key = ((pk < key) == wantmin) ? pk : key;
                    }
                    for (; j > 0; j >>= 1) {            // in-wave: shuffle
                        u64 pk = shfl_xor_u64(key, (int)j);
                        bool lower = ((tid & j) == 0);
                        bool wantmin = (((tid & k) == 0) == lower);
                        key = ((pk < key) == wantmin) ? pk : key;
                    }
                }
                if (tid < KOUT) {
                    float2 o = make_float2(0.0f, 0.0f);
                    if (tid < Kb) {
                        o.x = funmap((uint32_t)(key >> 32));
                        o.y = funmap((uint32_t)key);
                    }
                    outb[tid] = o;
                }
                continue;
            }

            // ---- exact fallback (statistically unreachable; guards exact) ----
            __syncthreads();
            if (tid == 0) { shcnt = 0u; shT = FNB - 1; }
            for (int i = tid; i < FNB; i += NT) hist[i] = 0u;
            __syncthreads();
            for (int i = tid; i < L; i += NT)
                atomicAdd(&hist[fmap(cp[i].x) >> 20], 1u);
            __syncthreads();
            if (tid == 0) {
                uint32_t run = 0;
                for (int g = 0; g < FNB; ++g) {
                    run += hist[g];
                    if (run >= (uint32_t)Kb) { shT = (uint32_t)g; break; }
                }
            }
            __syncthreads();
            const uint32_t T = shT;
            for (int i = tid; i < L; i += NT) {
                float2 c = cp[i];
                uint32_t kx = fmap(c.x);
                if ((kx >> 20) <= T) {
                    uint32_t p = atomicAdd(&shcnt, 1u);
                    if (p < FCAP) fcand[p] = ((u64)kx << 32) | fmap(c.y);
                }
            }
            __syncthreads();
            const int nn = (int)((shcnt < FCAP) ? shcnt : FCAP);
            for (int jj = Kb + tid; jj < KOUT; jj += NT)
                outb[jj] = make_float2(0.0f, 0.0f);
            for (int i = tid; i < nn; i += NT) {
                u64 ki = fcand[i];
                uint32_t r = 0;
                for (int jj = 0; jj < nn; ++jj) {
                    u64 kj = fcand[jj];
                    r += (kj < ki) || (kj == ki && jj < i);
                }
                if (r < (uint32_t)Kb)
                    outb[r] = make_float2(funmap((uint32_t)(ki >> 32)), funmap((uint32_t)ki));
            }
        }
    }
}

extern "C" void kernel_launch(void* const* d_in, const int* in_sizes, int n_in,
                              void* d_out, int out_size, void* d_ws, size_t ws_size,
                              hipStream_t stream) {
    const float* corners = (const float*)d_in[0];
    const int* lengths   = (const int*)d_in[1];
    float* out = (float*)d_out;
    const int B = in_sizes[1];
    const int M = in_sizes[0] / (B * 2);

    uint32_t* ctrs = (uint32_t*)d_ws;    // NSH counters, 64B apart
    hipMemsetAsync(ctrs, 0, NSH * 16 * sizeof(uint32_t), stream);
    topk_kernel<<<GRID, NT, 0, stream>>>(corners, lengths, out, ctrs, M, B);
}

// Round 14
// 24.114 us; speedup vs baseline: 2.1398x; 2.1398x over previous
//
#include <hip/hip_runtime.h>
#include <stdint.h>
#include <math.h>

typedef unsigned long long u64;

#define NT     1024
#define KOUT   512
#define DIRECT 1024     // L <= DIRECT: load rows directly, no filter
#define NBK    1024     // sort buckets
#define MAXB   48       // per-bucket guard
#define FNB    4096     // fallback histogram bins
#define FCAP   2048     // fallback candidate buffer

// Monotone float->uint32 map (order-preserving), exactly invertible.
__device__ __forceinline__ uint32_t fmap(float f) {
    uint32_t u = __float_as_uint(f);
    return (u & 0x80000000u) ? ~u : (u | 0x80000000u);
}
__device__ __forceinline__ float funmap(uint32_t m) {
    uint32_t u = (m & 0x80000000u) ? (m & 0x7fffffffu) : ~m;
    return __uint_as_float(u);
}
__device__ __forceinline__ u64 pack(float x, float y) {
    return ((u64)fmap(x) << 32) | (u64)fmap(y);
}

// Acklam inverse normal CDF (float); ~1e-3 accuracy, exactness guarded downstream.
__device__ __forceinline__ float norm_icdf(float p) {
    const float a1=-3.969683028665376e+01f,a2= 2.209460984245205e+02f,a3=-2.759285104469687e+02f,
                a4= 1.383577518672690e+02f,a5=-3.066479806614716e+01f,a6= 2.506628277459239e+00f;
    const float b1=-5.447609879822406e+01f,b2= 1.615858368580409e+02f,b3=-1.556989798598866e+02f,
                b4= 6.680131188771972e+01f,b5=-1.328068155288572e+01f;
    const float c1=-7.784894002430293e-03f,c2=-3.223964580411365e-01f,c3=-2.400758277161838e+00f,
                c4=-2.549732539343734e+00f,c5= 4.374664141464968e+00f,c6= 2.938163982698783e+00f;
    const float d1= 7.784695709041462e-03f,d2= 3.224671290700398e-01f,d3= 2.445134137142996e+00f,
                d4= 3.754408661907416e+00f;
    if (p < 0.02425f) {
        float q = sqrtf(-2.0f * logf(p));
        return (((((c1*q+c2)*q+c3)*q+c4)*q+c5)*q+c6) / ((((d1*q+d2)*q+d3)*q+d4)*q+1.0f);
    } else if (p <= 0.97575f) {
        float q = p - 0.5f, r = q*q;
        return (((((a1*r+a2)*r+a3)*r+a4)*r+a5)*r+a6)*q / (((((b1*r+b2)*r+b3)*r+b4)*r+b5)*r+1.0f);
    } else {
        float q = sqrtf(-2.0f * logf(1.0f - p));
        return -(((((c1*q+c2)*q+c3)*q+c4)*q+c5)*q+c6) / ((((d1*q+d2)*q+d3)*q+d4)*q+1.0f);
    }
}

__global__ __launch_bounds__(NT) void topk_kernel(
    const float* __restrict__ corners, const int* __restrict__ lengths,
    float* __restrict__ out, int M)
{
    const int b = blockIdx.x;
    const int tid = threadIdx.x;
    int L = lengths[b];
    if (L < 0) L = 0;
    if (L > M) L = M;
    const int Kb = (L < KOUT) ? L : KOUT;
    float2* outb = (float2*)(out + (size_t)b * (2 * KOUT));

    if (L == 0) {
        if (tid < KOUT) outb[tid] = make_float2(0.0f, 0.0f);
        return;
    }

    __shared__ u64 sbuf[NT];         // candidate buffer / scatter target
    __shared__ uint32_t bh[NBK];     // bucket counts
    __shared__ uint32_t sc[NBK];     // bucket starts (exclusive scan)
    __shared__ uint32_t wsum[16];
    __shared__ uint32_t hist[FNB];   // fallback only
    __shared__ u64 fcand[FCAP];      // fallback only
    __shared__ uint32_t shcnt, shT, ovf;

    const float2* cp = (const float2*)corners + (size_t)b * M;
    bool fb = false;
    uint32_t n = 0;

    if (L <= DIRECT) {
        // ---- direct path: every valid row is a candidate ----
        n = (uint32_t)L;
        sbuf[tid] = (tid < L) ? pack(cp[tid].x, cp[tid].y) : ~0ull;
    } else {
        // ---- filtered path: keep x <= tau(L), expected n ~ 768 +- 28 ----
        if (tid == 0) shcnt = 0u;
        __syncthreads();
        const float tau = norm_icdf(768.0f / (float)L) + 0.01f;
        const int lane = tid & 63;
        const float4* cp4 = (const float4*)cp;
        const int nv = L >> 1;

        for (int i = tid; i < nv; i += NT) {
            float4 v = cp4[i];
            bool c0k = (v.x <= tau), c1k = (v.z <= tau);
            u64 m0 = __ballot(c0k), m1 = __ballot(c1k);
            if (m0 | m1) {
                int c0 = __popcll(m0);
                uint32_t base = 0;
                if (lane == 0) base = atomicAdd(&shcnt, (uint32_t)(c0 + __popcll(m1)));
                base = __shfl(base, 0, 64);
                u64 lt = ((u64)1 << lane) - 1ull;
                if (c0k) {
                    uint32_t s = base + (uint32_t)__popcll(m0 & lt);
                    if (s < NT) sbuf[s] = pack(v.x, v.y);
                }
                if (c1k) {
                    uint32_t s = base + (uint32_t)(c0 + __popcll(m1 & lt));
                    if (s < NT) sbuf[s] = pack(v.z, v.w);
                }
            }
        }
        if ((L & 1) && tid == 0) {
            float2 c = cp[L - 1];
            if (c.x <= tau) {
                uint32_t s = atomicAdd(&shcnt, 1u);
                if (s < NT) sbuf[s] = pack(c.x, c.y);
            }
        }
        __syncthreads();
        n = shcnt;
        if (n < (uint32_t)Kb || n > NT) fb = true;     // block-uniform
        else if (tid >= (int)n) sbuf[tid] = ~0ull;     // sentinel-pad
    }

    if (!fb) {
        __syncthreads();   // sbuf fully populated

        // ---- bucketed counting-sort rank (no bitonic network) ----
        u64 key = sbuf[tid];
        const bool valid = (tid < (int)n);
        uint32_t bkt = 0;
        if (valid) {
            float x = funmap((uint32_t)(key >> 32));
            float p = 0.5f * (1.0f + erff(x * 0.70710678f));   // Phi(x)
            float s = (L > DIRECT) ? ((float)L * ((float)NBK / 768.0f))
                                   : (float)NBK;
            float fp = p * s;
            uint32_t bb = (uint32_t)fp;
            bkt = (bb > (NBK - 1u)) ? (NBK - 1u) : bb;
        }

        bh[tid] = 0u;
        if (tid == 0) ovf = 0u;
        __syncthreads();
        if (valid) atomicAdd(&bh[bkt], 1u);
        __syncthreads();

        // exclusive scan of bh -> sc (wave shuffle scan + wave-sum scan)
        {
            const uint32_t c = bh[tid];
            const int lane = tid & 63, wid = tid >> 6;
            uint32_t v = c;
            for (int off = 1; off < 64; off <<= 1) {
                uint32_t t2 = __shfl_up(v, (unsigned)off, 64);
                if (lane >= off) v += t2;
            }
            if (lane == 63) wsum[wid] = v;
            __syncthreads();
            if (tid < 16) {
                uint32_t xv = wsum[tid];
                for (int off = 1; off < 16; off <<= 1) {
                    uint32_t t2 = __shfl_up(xv, (unsigned)off, 16);
                    if (tid >= off) xv += t2;
                }
                wsum[tid] = xv;
            }
            __syncthreads();
            const uint32_t woff = (wid > 0) ? wsum[wid - 1] : 0u;
            sc[tid] = v + woff - c;
        }
        __syncthreads();
        bh[tid] = 0u;
        __syncthreads();

        // scatter by bucket (keys already in registers; sbuf reusable)
        uint32_t pos = 0;
        if (valid) {
            uint32_t off = atomicAdd(&bh[bkt], 1u);
            pos = sc[bkt] + off;
            sbuf[pos] = key;
        }
        __syncthreads();
        if (valid && bh[bkt] > MAXB) ovf = 1u;   // benign race, all write 1
        __syncthreads();

        if (ovf == 0u) {   // block-uniform
            // exact global rank = bucket start + rank within bucket
            uint32_t rank = 0;
            if (valid) {
                const uint32_t s0 = sc[bkt];
                const uint32_t cnt = bh[bkt];
                uint32_t r = 0;
                for (uint32_t m = 0; m < cnt; ++m) {
                    u64 kj = sbuf[s0 + m];
                    r += (kj < key) || (kj == key && (s0 + m) < pos);
                }
                rank = s0 + r;
            }
            if (tid >= Kb && tid < KOUT)
                outb[tid] = make_float2(0.0f, 0.0f);
            if (valid && rank < (uint32_t)Kb) {
                float2 o;
                o.x = funmap((uint32_t)(key >> 32));
                o.y = funmap((uint32_t)key);
                outb[rank] = o;
            }
            return;
        }
        // bucket overflow (statistically unreachable) -> exact fallback below
    }

    // ---- exact fallback (statistically unreachable; guards exact) ----
    __syncthreads();
    if (tid == 0) { shcnt = 0u; shT = FNB - 1; }
    for (int i = tid; i < FNB; i += NT) hist[i] = 0u;
    __syncthreads();
    for (int i = tid; i < L; i += NT)
        atomicAdd(&hist[fmap(cp[i].x) >> 20], 1u);
    __syncthreads();
    if (tid == 0) {
        uint32_t run = 0;
        for (int g = 0; g < FNB; ++g) {
            run += hist[g];
            if (run >= (uint32_t)Kb) { shT = (uint32_t)g; break; }
        }
    }
    __syncthreads();
    const uint32_t T = shT;
    for (int i = tid; i < L; i += NT) {
        float2 c = cp[i];
        uint32_t kx = fmap(c.x);
        if ((kx >> 20) <= T) {
            uint32_t p = atomicAdd(&shcnt, 1u);
            if (p < FCAP) fcand[p] = ((u64)kx << 32) | fmap(c.y);
        }
    }
    __syncthreads();
    const int nn = (int)((shcnt < FCAP) ? shcnt : FCAP);
    for (int jj = Kb + tid; jj < KOUT; jj += NT)
        outb[jj] = make_float2(0.0f, 0.0f);
    for (int i = tid; i < nn; i += NT) {
        u64 ki = fcand[i];
        uint32_t r = 0;
        for (int jj = 0; jj < nn; ++jj) {
            u64 kj = fcand[jj];
            r += (kj < ki) || (kj == ki && jj < i);
        }
        if (r < (uint32_t)Kb)
            outb[r] = make_float2(funmap((uint32_t)(ki >> 32)), funmap((uint32_t)ki));
    }
}

extern "C" void kernel_launch(void* const* d_in, const int* in_sizes, int n_in,
                              void* d_out, int out_size, void* d_ws, size_t ws_size,
                              hipStream_t stream) {
    const float* corners = (const float*)d_in[0];
    const int* lengths   = (const int*)d_in[1];
    float* out = (float*)d_out;
    const int B = in_sizes[1];
    const int M = in_sizes[0] / (B * 2);
    topk_kernel<<<B, NT, 0, stream>>>(corners, lengths, out, M);
}